// Round 9
// baseline (61.155 us; speedup 1.0000x reference)
//
#include <hip/hip_runtime.h>

#define STN 9
#define CC 3
#define NPIX 9216
#define PLANE 82944           // 288*288
#define W4PL 57600            // float4 per (o,i) weight plane
#define LWB 900               // float4 per LDS weight buffer = 9o*16px*25/4

typedef float f4v __attribute__((ext_vector_type(4)));

__global__ __launch_bounds__(192)
void lfk9(const float* __restrict__ lf, const float* __restrict__ wts,
          const float* __restrict__ bias, float* __restrict__ out)
{
    __shared__ f4v ldsW[2][LWB];              // 28.8 KB, identity-packed [o][px][25]
    float* const ldsf = (float*)&ldsW[0][0];

    const int tid  = threadIdx.x;
    const int tile = blockIdx.x;              // 0..575
    const int oh   = tile / 6;
    const int tc   = tile - oh * 6;
    const int px   = tid & 15;
    const int b    = (tid >> 4) & 3;
    const int og   = tid >> 6;                // wave index 0..2
    const int g    = tile * 16 + px;
    const int ow   = tc * 16 + px;
    const int y0   = oh * 3 - 2;              // pt = pl = 2, no bottom/right pad
    const int x0   = ow * 3 - 2;
    const int xcl  = (x0 < 0) ? 0 : x0;
    const bool xneg = (x0 < 0);               // only px==0 in tc==0 blocks
    const bool tc0  = (tc == 0);              // block-uniform
    const bool oh0  = (oh == 0);              // block-uniform

    // ---- staging descriptors: 900 f4 over 192 threads (5 slots) ----
    const f4v* __restrict__ w4g = (const f4v*)wts;
    int sg[5], sl[5];
    #pragma unroll
    for (int j = 0; j < 5; ++j) {
        const int idx = tid + 192 * j;        // j<4 always < 900
        sl[j] = idx;
        const int o = idx / 100, rem = idx - o * 100;
        sg[j] = o * (9 * W4PL) + tile * 100 + rem;   // + i*W4PL at load time
    }

    f4v wr[5];
    auto loadWregs = [&](int i) {
        #pragma unroll
        for (int j = 0; j < 5; ++j)
            if (j < 4 || sl[j] < LWB) wr[j] = w4g[sg[j] + i * W4PL];
    };
    auto writeW = [&](int buf) {
        #pragma unroll
        for (int j = 0; j < 5; ++j)
            if (j < 4 || sl[j] < LWB) ldsW[buf][sl[j]] = wr[j];
    };

    // ---- patch sets: 3 c-sets, rolling refill ----
    f4v  Pv[3][5];
    float Pe[3][5];
    auto loadP = [&](int c, int i) {
        const float* rb = lf + ((b * 9 + i) * 3 + c) * PLANE + xcl;
        #pragma unroll
        for (int kh = 0; kh < 5; ++kh) {
            const int y = y0 + kh;
            if (!oh0 || y >= 0) {             // block-uniform
                const float* rp = rb + y * 288;
                f4v A; __builtin_memcpy(&A, rp, 16);
                Pv[c][kh] = A;
                Pe[c][kh] = rp[4];            // x0+4 <= 287 always: in-bounds
            } else {
                Pv[c][kh] = (f4v)0.f;
                Pe[c][kh] = 0.f;
            }
        }
    };

    float acc[3][3];                          // [oc][c]
    #pragma unroll
    for (int oc = 0; oc < 3; ++oc)
        #pragma unroll
        for (int c = 0; c < 3; ++c) acc[oc][c] = 0.f;

    // ---- prologue: stage weights(0), prefetch patches(0, all c) ----
    loadWregs(0);
    loadP(0, 0); loadP(1, 0); loadP(2, 0);
    writeW(0);
    __syncthreads();

    const int wbase = og * 1200 + px * 25;

    #pragma unroll 1
    for (int i = 0; i < 9; ++i) {
        const int buf = i & 1;
        const bool more = (i < 8);

        // weights for this i -> regs (reused across 3 c): ~75 b32 (fuse to read2)
        float w[3][25];
        const float* wp = ldsf + buf * 3600 + wbase;
        #pragma unroll
        for (int oc = 0; oc < 3; ++oc)
            #pragma unroll
            for (int k = 0; k < 25; ++k)
                w[oc][k] = wp[oc * 400 + k];

        if (more) loadWregs(i + 1);           // VMEM early (T14)

        #pragma unroll
        for (int c = 0; c < 3; ++c) {
            // build 5x5 window from this c's regs
            #pragma unroll
            for (int kh = 0; kh < 5; ++kh) {
                const f4v A = Pv[c][kh];
                const float e = Pe[c][kh];
                float q0, q1, q2, q3, q4;
                if (tc0) {
                    q0 = xneg ? 0.f : A.x;
                    q1 = xneg ? 0.f : A.y;
                    q2 = xneg ? A.x : A.z;
                    q3 = xneg ? A.y : A.w;
                    q4 = xneg ? A.z : e;
                } else {
                    q0 = A.x; q1 = A.y; q2 = A.z; q3 = A.w; q4 = e;
                }
                #pragma unroll
                for (int oc = 0; oc < 3; ++oc) {
                    acc[oc][c] = fmaf(w[oc][kh * 5 + 0], q0, acc[oc][c]);
                    acc[oc][c] = fmaf(w[oc][kh * 5 + 1], q1, acc[oc][c]);
                    acc[oc][c] = fmaf(w[oc][kh * 5 + 2], q2, acc[oc][c]);
                    acc[oc][c] = fmaf(w[oc][kh * 5 + 3], q3, acc[oc][c]);
                    acc[oc][c] = fmaf(w[oc][kh * 5 + 4], q4, acc[oc][c]);
                }
            }
            if (more) loadP(c, i + 1);        // refill freed set; hides under next c
        }

        if (more) {
            writeW(buf ^ 1);                  // stage weights(i+1)
            __syncthreads();                  // uniform condition: legal
        }
    }

    // ---- epilogue: bias + clip + store ----
    #pragma unroll
    for (int oc = 0; oc < 3; ++oc) {
        const int o = og * 3 + oc;
        const float bo = bias[o * NPIX + g];
        #pragma unroll
        for (int c = 0; c < 3; ++c) {
            float v = acc[oc][c] + bo;
            v = fminf(fmaxf(v, 0.f), 1.f);
            out[((b * STN + o) * CC + c) * NPIX + g] = v;
        }
    }
}

extern "C" void kernel_launch(void* const* d_in, const int* in_sizes, int n_in,
                              void* d_out, int out_size, void* d_ws, size_t ws_size,
                              hipStream_t stream) {
    const float* lf   = (const float*)d_in[0];
    const float* wts  = (const float*)d_in[1];
    const float* bias = (const float*)d_in[2];
    float* out = (float*)d_out;
    (void)d_ws; (void)ws_size; (void)in_sizes; (void)n_in; (void)out_size;

    dim3 grid(576);         // one block per 16-px tile; whole grid co-resident
    dim3 block(192);        // 16 px x 4 b x 3 og (og = wave)
    lfk9<<<grid, block, 0, stream>>>(lf, wts, bias, out);
}